// Round 10
// baseline (5431.752 us; speedup 1.0000x reference)
//
#include <hip/hip_runtime.h>
#include <hip/hip_bf16.h>

#define T_STEPS 512
#define BATCH   4096
#define ACT     16
#define HDIM    64
#define NSLICE  256

typedef short s8v __attribute__((ext_vector_type(8)));   // 8 bf16 MFMA A/B frag
typedef float f4v __attribute__((ext_vector_type(4)));   // MFMA C/D frag

#define MFMA16(A, B, C) __builtin_amdgcn_mfma_f32_16x16x32_bf16((A), (B), (C), 0, 0, 0)

__device__ __forceinline__ unsigned pkbf(float a, float b) {
    unsigned r;
    asm("v_cvt_pk_bf16_f32 %0, %1, %2" : "=v"(r) : "v"(a), "v"(b));
    return r;
}
__device__ __forceinline__ float hi16f(unsigned p) { return __builtin_bit_cast(float, p & 0xFFFF0000u); }
__device__ __forceinline__ unsigned short f2bf(float f) {
    unsigned u = __builtin_bit_cast(unsigned, f);
    u += 0x7FFFu + ((u >> 16) & 1u);
    return (unsigned short)(u >> 16);
}
__device__ __forceinline__ float bf2f(unsigned short b) {
    return __builtin_bit_cast(float, ((unsigned)b) << 16);
}
__device__ __forceinline__ float ftanh(float x) {
    float e = __expf(2.0f * x);
    return fmaf(-2.0f, __builtin_amdgcn_rcpf(e + 1.0f), 1.0f);
}
struct i4x { int a, b, c, d; };
// 4 f32 -> interleaved (hi,lo) bf16 pairs
__device__ __forceinline__ s8v pack4(f4v v) {
    unsigned p0 = pkbf(v[0], v[0]); float r0 = v[0] - hi16f(p0);
    unsigned p1 = pkbf(v[1], v[1]); float r1 = v[1] - hi16f(p1);
    unsigned p2 = pkbf(v[2], v[2]); float r2 = v[2] - hi16f(p2);
    unsigned p3 = pkbf(v[3], v[3]); float r3 = v[3] - hi16f(p3);
    i4x w{(int)pkbf(v[0], r0), (int)pkbf(v[1], r1), (int)pkbf(v[2], r2), (int)pkbf(v[3], r3)};
    return __builtin_bit_cast(s8v, w);
}
#define BAR() do { \
    asm volatile("s_waitcnt lgkmcnt(0)" ::: "memory"); \
    __builtin_amdgcn_s_barrier(); \
    asm volatile("" ::: "memory"); \
} while (0)

// Grid-partitioned producer/consumer:
//   blocks [0,256):   capture block for slice b (4 waves, t-sweep, publishes flags)
//   blocks [256,512): recur block for slice b-256 (4 waves, R8 channel-split chain)
__global__ __launch_bounds__(256, 2) void cell_k(
    const float* __restrict__ x,  const float* __restrict__ h0,
    const float* __restrict__ g,  const float* __restrict__ a,
    const float* __restrict__ Wc1, const float* __restrict__ bc1,
    const float* __restrict__ Wc2, const float* __restrict__ bc2,
    const float* __restrict__ Wp1, const float* __restrict__ bp1,
    const float* __restrict__ Wp2, const float* __restrict__ bp2,
    float* __restrict__ outs, float* __restrict__ hfin,
    float* __restrict__ capt, int* __restrict__ flags)
{
    const int tid = threadIdx.x;
    const int T   = tid >> 6;      // wave's channel tile
    const int l   = tid & 63;
    const int m   = l & 15;        // batch row within slice
    const int q   = l >> 4;        // k-group / D out-ch group

    if (blockIdx.x < NSLICE) {
        // ======================= CAPTURE BLOCK =======================
        __shared__ short t1x[16 * 132];   // [m][dup-k 0..127], stride 132 (2m banks)
        const int s  = blockIdx.x;
        const int b0 = s << 4;

        s8v C1[4], C2h[4], C2l[4];
        #pragma unroll
        for (int f = 0; f < 4; ++f)
            #pragma unroll
            for (int e = 0; e < 8; ++e) {
                const int j = f * 16 + q * 4 + (e >> 1);
                C1[f][e] = (short)f2bf(Wc1[j * 64 + 16 * T + m]);
                float v2 = Wc2[j * 64 + 16 * T + m];
                unsigned short h2 = f2bf(v2);
                C2h[f][e] = (short)h2;
                C2l[f][e] = (short)f2bf(v2 - bf2f(h2));
            }
        const f4v d1 = *(const f4v*)&bc1[16 * T + 4 * q];
        const f4v d2 = *(const f4v*)&bc2[16 * T + 4 * q];

        const float* xb = x + (long)(b0 + m) * 64 + 4 * q;
        f4v XA0 = *(const f4v*)(xb);
        f4v XA1 = *(const f4v*)(xb + 16);
        f4v XA2 = *(const f4v*)(xb + 32);
        f4v XA3 = *(const f4v*)(xb + 48);
        const float* xb1 = xb + (long)BATCH * 64;
        f4v XB0 = *(const f4v*)(xb1);
        f4v XB1 = *(const f4v*)(xb1 + 16);
        f4v XB2 = *(const f4v*)(xb1 + 32);
        f4v XB3 = *(const f4v*)(xb1 + 48);
        const float* xpA = xb + (long)2 * BATCH * 64;
        const float* xpB = xb + (long)3 * BATCH * 64;

        short*       t1w = &t1x[m * 132 + 32 * T + 8 * q];
        const short* t1r = &t1x[m * 132 + 8 * q];

#define CSTEP(tt, X0, X1, X2, X3, XPTR, ODD) do {                             \
    const int t_ = (tt);                                                      \
    s8v xf0 = pack4(X0), xf1 = pack4(X1), xf2 = pack4(X2), xf3 = pack4(X3);   \
    X0 = *(const f4v*)(XPTR);                                                 \
    X1 = *(const f4v*)(XPTR + 16);                                            \
    X2 = *(const f4v*)(XPTR + 32);                                            \
    X3 = *(const f4v*)(XPTR + 48);                                            \
    if (t_ + 4 < T_STEPS) XPTR += (long)2 * BATCH * 64;                       \
    f4v u0 = d1;                                                              \
    f4v u1 = {0.f, 0.f, 0.f, 0.f};                                            \
    u0 = MFMA16(C1[0], xf0, u0); u1 = MFMA16(C1[1], xf1, u1);                 \
    u0 = MFMA16(C1[2], xf2, u0); u1 = MFMA16(C1[3], xf3, u1);                 \
    f4v tv;                                                                   \
    _Pragma("unroll")                                                         \
    for (int r = 0; r < 4; ++r) tv[r] = ftanh(u0[r] + u1[r]);                 \
    *(s8v*)t1w = pack4(tv);                                                   \
    BAR();                                                                    \
    s8v tf0 = *(const s8v*)(t1r);                                             \
    s8v tf1 = *(const s8v*)(t1r + 32);                                        \
    s8v tf2 = *(const s8v*)(t1r + 64);                                        \
    s8v tf3 = *(const s8v*)(t1r + 96);                                        \
    f4v c0 = d2;                                                              \
    f4v c1 = {0.f, 0.f, 0.f, 0.f}, c2 = c1, c3 = c1;                          \
    c0 = MFMA16(C2h[0], tf0, c0); c1 = MFMA16(C2h[1], tf1, c1);               \
    c2 = MFMA16(C2h[2], tf2, c2); c3 = MFMA16(C2h[3], tf3, c3);               \
    c0 = MFMA16(C2l[0], tf0, c0); c1 = MFMA16(C2l[1], tf1, c1);               \
    c2 = MFMA16(C2l[2], tf2, c2); c3 = MFMA16(C2l[3], tf3, c3);               \
    f4v zv;                                                                   \
    _Pragma("unroll")                                                         \
    for (int r = 0; r < 4; ++r) zv[r] = ftanh((c0[r] + c1[r]) + (c2[r] + c3[r])); \
    const long idx = ((long)t_ * BATCH + b0 + m) * 64 + 16 * T + 4 * q;       \
    _Pragma("unroll")                                                         \
    for (int r = 0; r < 4; ++r)                                               \
        __hip_atomic_store(&capt[idx + r], zv[r], __ATOMIC_RELAXED,           \
                           __HIP_MEMORY_SCOPE_AGENT);                         \
    if (ODD) {                                                                \
        asm volatile("s_waitcnt vmcnt(0)" ::: "memory");                      \
        __syncthreads();                                                      \
        if (tid == 0)                                                         \
            __hip_atomic_store(&flags[s], t_ + 1, __ATOMIC_RELEASE,           \
                               __HIP_MEMORY_SCOPE_AGENT);                     \
    } else {                                                                  \
        BAR();                                                                \
    }                                                                         \
} while (0)

        for (int t = 0; t < T_STEPS; t += 2) {
            CSTEP(t,     XA0, XA1, XA2, XA3, xpA, 0);
            CSTEP(t + 1, XB0, XB1, XB2, XB3, xpB, 1);
        }
#undef CSTEP

    } else {
        // ======================= RECUR BLOCK =======================
        __shared__ s8v hx[4][64];
        __shared__ s8v t1x2[4][64];
        const int s  = blockIdx.x - NSLICE;
        const int b0 = s << 4;

        s8v W1[5], W2h[4], W2l[4];
        #pragma unroll
        for (int f = 0; f < 4; ++f)
            #pragma unroll
            for (int e = 0; e < 8; ++e) {
                const int j = f * 16 + q * 4 + (e >> 1);
                W1[f][e] = (short)f2bf(Wp1[j * 64 + 16 * T + m]);
                float v2 = Wp2[j * 64 + 16 * T + m];
                unsigned short h2 = f2bf(v2);
                W2h[f][e] = (short)h2;
                W2l[f][e] = (short)f2bf(v2 - bf2f(h2));
            }
        #pragma unroll
        for (int e = 0; e < 8; ++e) {
            const int j = 64 + q * 4 + (e >> 1);
            W1[4][e] = (short)f2bf(Wp1[j * 64 + 16 * T + m]);
        }
        const f4v b1v = *(const f4v*)&bp1[16 * T + 4 * q];
        const f4v b2v = *(const f4v*)&bp2[16 * T + 4 * q];

        const long zoff = (long)(b0 + m) * 64 + 16 * T + 4 * q;
        const long aoff = (long)(b0 + m) * ACT + 4 * q;
        const long goff = (long)(b0 + m);

        hx[T][l] = pack4(*(const f4v*)&h0[zoff]);
        __syncthreads();

        // wait for z1[0..15] then preload depth-8 rings
        int fl = __hip_atomic_load(&flags[s], __ATOMIC_RELAXED, __HIP_MEMORY_SCOPE_AGENT);
        while (fl < 16) {
            __builtin_amdgcn_s_sleep(8);
            fl = __hip_atomic_load(&flags[s], __ATOMIC_ACQUIRE, __HIP_MEMORY_SCOPE_AGENT);
        }
        asm volatile("" ::: "memory");

#define ZLOAD(tn) ({                                                          \
    f4v z_;                                                                   \
    const long bidx = (long)(tn) * BATCH * 64 + zoff;                         \
    _Pragma("unroll")                                                         \
    for (int r = 0; r < 4; ++r)                                               \
        z_[r] = __hip_atomic_load(&capt[bidx + r], __ATOMIC_RELAXED,          \
                                  __HIP_MEMORY_SCOPE_AGENT);                  \
    z_; })

        f4v zP0 = ZLOAD(0), zP1 = ZLOAD(1), zP2 = ZLOAD(2), zP3 = ZLOAD(3);
        f4v zP4 = ZLOAD(4), zP5 = ZLOAD(5), zP6 = ZLOAD(6), zP7 = ZLOAD(7);
        f4v aP0 = *(const f4v*)&a[0 * (long)BATCH * ACT + aoff];
        f4v aP1 = *(const f4v*)&a[1 * (long)BATCH * ACT + aoff];
        f4v aP2 = *(const f4v*)&a[2 * (long)BATCH * ACT + aoff];
        f4v aP3 = *(const f4v*)&a[3 * (long)BATCH * ACT + aoff];
        f4v aP4 = *(const f4v*)&a[4 * (long)BATCH * ACT + aoff];
        f4v aP5 = *(const f4v*)&a[5 * (long)BATCH * ACT + aoff];
        f4v aP6 = *(const f4v*)&a[6 * (long)BATCH * ACT + aoff];
        f4v aP7 = *(const f4v*)&a[7 * (long)BATCH * ACT + aoff];
        float gP0 = g[0 * (long)BATCH + goff], gP1 = g[1 * (long)BATCH + goff];
        float gP2 = g[2 * (long)BATCH + goff], gP3 = g[3 * (long)BATCH + goff];
        float gP4 = g[4 * (long)BATCH + goff], gP5 = g[5 * (long)BATCH + goff];
        float gP6 = g[6 * (long)BATCH + goff], gP7 = g[7 * (long)BATCH + goff];

        int flagNext = __hip_atomic_load(&flags[s], __ATOMIC_RELAXED, __HIP_MEMORY_SCOPE_AGENT);
        float* outp = &outs[zoff];
        f4v hl = {0.f, 0.f, 0.f, 0.f};

#define RSTEP(tt, ZP, AP, GP) do {                                            \
    const s8v hf0 = hx[0][l];                                                 \
    const s8v hf1 = hx[1][l];                                                 \
    const s8v hf2 = hx[2][l];                                                 \
    const s8v hf3 = hx[3][l];                                                 \
    const s8v afr = pack4(AP);                                                \
    f4v p0 = b1v;                                                             \
    f4v p1 = {0.f, 0.f, 0.f, 0.f}, p2 = p1;                                   \
    p0 = MFMA16(W1[0], hf0, p0);                                              \
    p1 = MFMA16(W1[1], hf1, p1);                                              \
    p2 = MFMA16(W1[2], hf2, p2);                                              \
    p0 = MFMA16(W1[3], hf3, p0);                                              \
    p1 = MFMA16(W1[4], afr, p1);                                              \
    f4v tv;                                                                   \
    _Pragma("unroll")                                                         \
    for (int r = 0; r < 4; ++r) tv[r] = ftanh((p0[r] + p1[r]) + p2[r]);       \
    t1x2[T][l] = pack4(tv);                                                   \
    BAR();                                                                    \
    const s8v tf0 = t1x2[0][l];                                               \
    const s8v tf1 = t1x2[1][l];                                               \
    const s8v tf2 = t1x2[2][l];                                               \
    const s8v tf3 = t1x2[3][l];                                               \
    f4v c0 = b2v;                                                             \
    f4v c1 = {0.f, 0.f, 0.f, 0.f}, c2 = c1, c3 = c1;                          \
    c0 = MFMA16(W2h[0], tf0, c0); c1 = MFMA16(W2h[1], tf1, c1);               \
    c2 = MFMA16(W2h[2], tf2, c2); c3 = MFMA16(W2h[3], tf3, c3);               \
    c0 = MFMA16(W2l[0], tf0, c0); c1 = MFMA16(W2l[1], tf1, c1);               \
    c2 = MFMA16(W2l[2], tf2, c2); c3 = MFMA16(W2l[3], tf3, c3);               \
    f4v hv;                                                                   \
    _Pragma("unroll")                                                         \
    for (int r = 0; r < 4; ++r) {                                             \
        float z2 = ftanh((c0[r] + c1[r]) + (c2[r] + c3[r]));                  \
        hv[r] = fmaf(GP, z2 - ZP[r], ZP[r]);                                  \
    }                                                                         \
    *(f4v*)outp = hv;                                                         \
    outp += (long)BATCH * HDIM;                                               \
    hl = hv;                                                                  \
    hx[T][l] = pack4(hv);                                                     \
    {                                                                         \
        const long tn = ((tt) + 8 < T_STEPS) ? (tt) + 8 : T_STEPS - 1;        \
        ZP = ZLOAD(tn);                                                       \
        AP = *(const f4v*)&a[tn * (long)BATCH * ACT + aoff];                  \
        GP = g[tn * (long)BATCH + goff];                                      \
    }                                                                         \
    BAR();                                                                    \
} while (0)

        for (int t = 0; t < T_STEPS; t += 8) {
            const int target = (t + 16 < T_STEPS) ? t + 16 : T_STEPS;
            if (flagNext < target) {
                do {
                    __builtin_amdgcn_s_sleep(4);
                    flagNext = __hip_atomic_load(&flags[s], __ATOMIC_ACQUIRE,
                                                 __HIP_MEMORY_SCOPE_AGENT);
                } while (flagNext < target);
            }
            asm volatile("" ::: "memory");
            flagNext = __hip_atomic_load(&flags[s], __ATOMIC_RELAXED,
                                         __HIP_MEMORY_SCOPE_AGENT);   // early, for next superstep
            RSTEP(t + 0, zP0, aP0, gP0);
            RSTEP(t + 1, zP1, aP1, gP1);
            RSTEP(t + 2, zP2, aP2, gP2);
            RSTEP(t + 3, zP3, aP3, gP3);
            RSTEP(t + 4, zP4, aP4, gP4);
            RSTEP(t + 5, zP5, aP5, gP5);
            RSTEP(t + 6, zP6, aP6, gP6);
            RSTEP(t + 7, zP7, aP7, gP7);
        }
#undef RSTEP
#undef ZLOAD

        *(f4v*)&hfin[zoff] = hl;
    }
}

extern "C" void kernel_launch(void* const* d_in, const int* in_sizes, int n_in,
                              void* d_out, int out_size, void* d_ws, size_t ws_size,
                              hipStream_t stream) {
    const float* x   = (const float*)d_in[0];
    const float* h0  = (const float*)d_in[1];
    const float* g   = (const float*)d_in[2];
    const float* a   = (const float*)d_in[3];
    const float* Wc1 = (const float*)d_in[4];
    const float* bc1 = (const float*)d_in[5];
    const float* Wc2 = (const float*)d_in[6];
    const float* bc2 = (const float*)d_in[7];
    const float* Wp1 = (const float*)d_in[8];
    const float* bp1 = (const float*)d_in[9];
    const float* Wp2 = (const float*)d_in[10];
    const float* bp2 = (const float*)d_in[11];

    float* outs = (float*)d_out;
    float* hfin = outs + (long)T_STEPS * BATCH * HDIM;
    float* capt = hfin + (long)BATCH * HDIM;
    int* flags  = (int*)d_ws;

    hipMemsetAsync(flags, 0, NSLICE * sizeof(int), stream);
    cell_k<<<2 * NSLICE, 256, 0, stream>>>(
        x, h0, g, a, Wc1, bc1, Wc2, bc2, Wp1, bp1, Wp2, bp2, outs, hfin, capt, flags);
}

// Round 11
// 1159.650 us; speedup vs baseline: 4.6840x; 4.6840x over previous
//
#include <hip/hip_runtime.h>
#include <hip/hip_bf16.h>

#define T_STEPS 512
#define BATCH   4096
#define ACT     16
#define HDIM    64

typedef short s8v __attribute__((ext_vector_type(8)));   // 8 bf16 MFMA A/B frag
typedef float f4v __attribute__((ext_vector_type(4)));   // MFMA C/D frag

#define MFMA16(A, B, C) __builtin_amdgcn_mfma_f32_16x16x32_bf16((A), (B), (C), 0, 0, 0)

__device__ __forceinline__ unsigned pkbf(float a, float b) {
    unsigned r;
    asm("v_cvt_pk_bf16_f32 %0, %1, %2" : "=v"(r) : "v"(a), "v"(b));
    return r;
}
__device__ __forceinline__ float hi16f(unsigned p) { return __builtin_bit_cast(float, p & 0xFFFF0000u); }
__device__ __forceinline__ unsigned short f2bf(float f) {
    unsigned u = __builtin_bit_cast(unsigned, f);
    u += 0x7FFFu + ((u >> 16) & 1u);
    return (unsigned short)(u >> 16);
}
__device__ __forceinline__ float bf2f(unsigned short b) {
    return __builtin_bit_cast(float, ((unsigned)b) << 16);
}
__device__ __forceinline__ float ftanh(float x) {
    float e = __expf(2.0f * x);
    return fmaf(-2.0f, __builtin_amdgcn_rcpf(e + 1.0f), 1.0f);
}
struct i4x { int a, b, c, d; };
// 4 f32 -> interleaved (hi,lo) bf16 pairs
__device__ __forceinline__ s8v pack4(f4v v) {
    unsigned p0 = pkbf(v[0], v[0]); float r0 = v[0] - hi16f(p0);
    unsigned p1 = pkbf(v[1], v[1]); float r1 = v[1] - hi16f(p1);
    unsigned p2 = pkbf(v[2], v[2]); float r2 = v[2] - hi16f(p2);
    unsigned p3 = pkbf(v[3], v[3]); float r3 = v[3] - hi16f(p3);
    i4x w{(int)pkbf(v[0], r0), (int)pkbf(v[1], r1), (int)pkbf(v[2], r2), (int)pkbf(v[3], r3)};
    return __builtin_bit_cast(s8v, w);
}
#define BAR() do { \
    asm volatile("s_waitcnt lgkmcnt(0)" ::: "memory"); \
    __builtin_amdgcn_s_barrier(); \
    asm volatile("" ::: "memory"); \
} while (0)

// ================= K1: capture (z1 for all T*B rows) =================
// grid-strided 16-row tiles, all state in registers; 512 blocks = 2/CU.
__global__ __launch_bounds__(256, 2) void capture_k(
    const float* __restrict__ x,
    const float* __restrict__ Wc1, const float* __restrict__ bc1,
    const float* __restrict__ Wc2, const float* __restrict__ bc2,
    float* __restrict__ capt)
{
    const int tid = threadIdx.x;
    const int l   = tid & 63;
    const int m   = l & 15;
    const int q   = l >> 4;
    const int gw  = blockIdx.x * 4 + (tid >> 6);   // 0..2047
    const int NW  = 2048;
    const long NT = (long)T_STEPS * BATCH / 16;    // 131072 tiles

    s8v C1[4][4], C2h[4][4], C2l[4][4];
    f4v d1v[4], d2v[4];
    #pragma unroll
    for (int T = 0; T < 4; ++T) {
        #pragma unroll
        for (int f = 0; f < 4; ++f) {
            #pragma unroll
            for (int e = 0; e < 8; ++e) {
                const int j = f * 16 + q * 4 + (e >> 1);
                C1[T][f][e] = (short)f2bf(Wc1[j * 64 + 16 * T + m]);
                float v2 = Wc2[j * 64 + 16 * T + m];
                unsigned short h2 = f2bf(v2);
                C2h[T][f][e] = (short)h2;
                C2l[T][f][e] = (short)f2bf(v2 - bf2f(h2));
            }
        }
        d1v[T] = *(const f4v*)&bc1[16 * T + 4 * q];
        d2v[T] = *(const f4v*)&bc2[16 * T + 4 * q];
    }

    long tile = gw;
    if (tile >= NT) return;
    f4v XC[4];
    #pragma unroll
    for (int f = 0; f < 4; ++f)
        XC[f] = *(const f4v*)&x[(tile * 16 + m) * 64 + 16 * f + 4 * q];

    for (; tile < NT; tile += NW) {
        const long nxt = (tile + NW < NT) ? tile + NW : tile;
        f4v XN[4];
        #pragma unroll
        for (int f = 0; f < 4; ++f)
            XN[f] = *(const f4v*)&x[(nxt * 16 + m) * 64 + 16 * f + 4 * q];

        s8v xf[4];
        #pragma unroll
        for (int f = 0; f < 4; ++f) xf[f] = pack4(XC[f]);

        s8v tcf[4];
        #pragma unroll
        for (int T = 0; T < 4; ++T) {
            f4v u0 = d1v[T];
            f4v u1 = {0.f, 0.f, 0.f, 0.f};
            u0 = MFMA16(C1[T][0], xf[0], u0);
            u1 = MFMA16(C1[T][1], xf[1], u1);
            u0 = MFMA16(C1[T][2], xf[2], u0);
            u1 = MFMA16(C1[T][3], xf[3], u1);
            f4v tv;
            #pragma unroll
            for (int r = 0; r < 4; ++r) tv[r] = ftanh(u0[r] + u1[r]);
            tcf[T] = pack4(tv);
        }
        #pragma unroll
        for (int T = 0; T < 4; ++T) {
            f4v c0 = d2v[T];
            f4v c1 = {0.f, 0.f, 0.f, 0.f}, c2 = c1, c3 = c1;
            c0 = MFMA16(C2h[T][0], tcf[0], c0);
            c1 = MFMA16(C2h[T][1], tcf[1], c1);
            c2 = MFMA16(C2h[T][2], tcf[2], c2);
            c3 = MFMA16(C2h[T][3], tcf[3], c3);
            c0 = MFMA16(C2l[T][0], tcf[0], c0);
            c1 = MFMA16(C2l[T][1], tcf[1], c1);
            c2 = MFMA16(C2l[T][2], tcf[2], c2);
            c3 = MFMA16(C2l[T][3], tcf[3], c3);
            f4v zv;
            #pragma unroll
            for (int r = 0; r < 4; ++r) zv[r] = ftanh((c0[r] + c1[r]) + (c2[r] + c3[r]));
            *(f4v*)&capt[(tile * 16 + m) * 64 + 16 * T + 4 * q] = zv;
        }
        #pragma unroll
        for (int f = 0; f < 4; ++f) XC[f] = XN[f];
    }
}

// ================= K2: recurrence, dual-slice ILP =================
// 128 blocks x 4 waves; wave T owns channel tile T for TWO batch slices.
// Two independent chains per wave hide each other's latencies.
__global__ __launch_bounds__(256, 1) void recur_k(
    const float* __restrict__ h0, const float* __restrict__ g,
    const float* __restrict__ a,  const float* __restrict__ Wp1,
    const float* __restrict__ bp1, const float* __restrict__ Wp2,
    const float* __restrict__ bp2, const float* __restrict__ z1,
    float* __restrict__ outs, float* __restrict__ hfin)
{
    __shared__ s8v hx[2][4][64];
    __shared__ s8v t1x[2][4][64];

    const int tid = threadIdx.x;
    const int T   = tid >> 6;      // owned channel tile
    const int l   = tid & 63;
    const int m   = l & 15;
    const int q   = l >> 4;
    const int b0  = blockIdx.x << 5;   // 32 rows = 2 slices

    // ---- own-tile weights (shared by both slices) ----
    s8v W1[5], W2h[4], W2l[4];
    #pragma unroll
    for (int f = 0; f < 4; ++f)
        #pragma unroll
        for (int e = 0; e < 8; ++e) {
            const int j = f * 16 + q * 4 + (e >> 1);
            W1[f][e] = (short)f2bf(Wp1[j * 64 + 16 * T + m]);
            float v2 = Wp2[j * 64 + 16 * T + m];
            unsigned short h2 = f2bf(v2);
            W2h[f][e] = (short)h2;
            W2l[f][e] = (short)f2bf(v2 - bf2f(h2));
        }
    #pragma unroll
    for (int e = 0; e < 8; ++e) {
        const int j = 64 + q * 4 + (e >> 1);
        W1[4][e] = (short)f2bf(Wp1[j * 64 + 16 * T + m]);
    }
    const f4v b1v = *(const f4v*)&bp1[16 * T + 4 * q];
    const f4v b2v = *(const f4v*)&bp2[16 * T + 4 * q];

    // per-lane stream offsets, slice 0 and 1
    const long zf0 = (long)(b0 + m) * 64 + 16 * T + 4 * q;
    const long zf1 = zf0 + 16 * 64;
    const long af0_ = (long)(b0 + m) * ACT + 4 * q;
    const long af1_ = af0_ + 16 * ACT;
    const long gf0 = (long)(b0 + m);
    const long gf1 = gf0 + 16;

    hx[0][T][l] = pack4(*(const f4v*)&h0[zf0]);
    hx[1][T][l] = pack4(*(const f4v*)&h0[zf1]);

    // depth-2 register rings (slot A = even t, slot B = odd t)
    f4v z0A = *(const f4v*)&z1[zf0];
    f4v z0B = *(const f4v*)&z1[(long)BATCH * 64 + zf0];
    f4v z1A = *(const f4v*)&z1[zf1];
    f4v z1B = *(const f4v*)&z1[(long)BATCH * 64 + zf1];
    f4v a0A = *(const f4v*)&a[af0_];
    f4v a0B = *(const f4v*)&a[(long)BATCH * ACT + af0_];
    f4v a1A = *(const f4v*)&a[af1_];
    f4v a1B = *(const f4v*)&a[(long)BATCH * ACT + af1_];
    float g0A = g[gf0], g0B = g[(long)BATCH + gf0];
    float g1A = g[gf1], g1B = g[(long)BATCH + gf1];

    float* out0 = &outs[zf0];
    float* out1 = &outs[zf1];
    f4v hl0 = {0.f, 0.f, 0.f, 0.f}, hl1 = hl0;
    __syncthreads();

#define RSTEP(tt, Z0, A0, G0, Z1v, A1, G1) do {                               \
    /* ---- phase 1: L1 for both slices ---- */                               \
    const s8v h00 = hx[0][0][l];                                              \
    const s8v h01 = hx[0][1][l];                                              \
    const s8v h02 = hx[0][2][l];                                              \
    const s8v h03 = hx[0][3][l];                                              \
    const s8v h10 = hx[1][0][l];                                              \
    const s8v h11 = hx[1][1][l];                                              \
    const s8v h12 = hx[1][2][l];                                              \
    const s8v h13 = hx[1][3][l];                                              \
    const s8v af0 = pack4(A0);                                                \
    const s8v af1 = pack4(A1);                                                \
    f4v p00 = b1v, p10 = b1v;                                                 \
    f4v p01 = {0.f, 0.f, 0.f, 0.f}, p02 = p01, p11 = p01, p12 = p01;          \
    p00 = MFMA16(W1[0], h00, p00);  p10 = MFMA16(W1[0], h10, p10);            \
    p01 = MFMA16(W1[1], h01, p01);  p11 = MFMA16(W1[1], h11, p11);            \
    p02 = MFMA16(W1[2], h02, p02);  p12 = MFMA16(W1[2], h12, p12);            \
    p00 = MFMA16(W1[3], h03, p00);  p10 = MFMA16(W1[3], h13, p10);            \
    p01 = MFMA16(W1[4], af0, p01);  p11 = MFMA16(W1[4], af1, p11);            \
    f4v tv0, tv1;                                                             \
    _Pragma("unroll")                                                         \
    for (int r = 0; r < 4; ++r) {                                             \
        tv0[r] = ftanh((p00[r] + p01[r]) + p02[r]);                           \
        tv1[r] = ftanh((p10[r] + p11[r]) + p12[r]);                           \
    }                                                                         \
    t1x[0][T][l] = pack4(tv0);                                                \
    t1x[1][T][l] = pack4(tv1);                                                \
    BAR();                                                                    \
    /* ---- phase 2: L2 + blend for both slices ---- */                       \
    const s8v t00 = t1x[0][0][l];                                             \
    const s8v t01 = t1x[0][1][l];                                             \
    const s8v t02 = t1x[0][2][l];                                             \
    const s8v t03 = t1x[0][3][l];                                             \
    const s8v t10 = t1x[1][0][l];                                             \
    const s8v t11 = t1x[1][1][l];                                             \
    const s8v t12 = t1x[1][2][l];                                             \
    const s8v t13 = t1x[1][3][l];                                             \
    f4v c00 = b2v, c10 = b2v;                                                 \
    f4v c01 = {0.f, 0.f, 0.f, 0.f}, c02 = c01, c03 = c01;                     \
    f4v c11 = c01, c12 = c01, c13 = c01;                                      \
    c00 = MFMA16(W2h[0], t00, c00);  c10 = MFMA16(W2h[0], t10, c10);          \
    c01 = MFMA16(W2h[1], t01, c01);  c11 = MFMA16(W2h[1], t11, c11);          \
    c02 = MFMA16(W2h[2], t02, c02);  c12 = MFMA16(W2h[2], t12, c12);          \
    c03 = MFMA16(W2h[3], t03, c03);  c13 = MFMA16(W2h[3], t13, c13);          \
    c00 = MFMA16(W2l[0], t00, c00);  c10 = MFMA16(W2l[0], t10, c10);          \
    c01 = MFMA16(W2l[1], t01, c01);  c11 = MFMA16(W2l[1], t11, c11);          \
    c02 = MFMA16(W2l[2], t02, c02);  c12 = MFMA16(W2l[2], t12, c12);          \
    c03 = MFMA16(W2l[3], t03, c03);  c13 = MFMA16(W2l[3], t13, c13);          \
    f4v hv0, hv1;                                                             \
    _Pragma("unroll")                                                         \
    for (int r = 0; r < 4; ++r) {                                             \
        float z20 = ftanh((c00[r] + c01[r]) + (c02[r] + c03[r]));             \
        float z21 = ftanh((c10[r] + c11[r]) + (c12[r] + c13[r]));             \
        hv0[r] = fmaf(G0, z20 - Z0[r], Z0[r]);                                \
        hv1[r] = fmaf(G1, z21 - Z1v[r], Z1v[r]);                              \
    }                                                                         \
    *(f4v*)out0 = hv0;  out0 += (long)BATCH * HDIM;                           \
    *(f4v*)out1 = hv1;  out1 += (long)BATCH * HDIM;                           \
    hl0 = hv0; hl1 = hv1;                                                     \
    hx[0][T][l] = pack4(hv0);                                                 \
    hx[1][T][l] = pack4(hv1);                                                 \
    /* ---- refill slot for tt+2 ---- */                                      \
    {                                                                         \
        const long tn = ((tt) + 2 < T_STEPS) ? (tt) + 2 : T_STEPS - 1;        \
        Z0  = *(const f4v*)&z1[tn * (long)BATCH * 64 + zf0];                  \
        Z1v = *(const f4v*)&z1[tn * (long)BATCH * 64 + zf1];                  \
        A0  = *(const f4v*)&a[tn * (long)BATCH * ACT + af0_];                 \
        A1  = *(const f4v*)&a[tn * (long)BATCH * ACT + af1_];                 \
        G0  = g[tn * (long)BATCH + gf0];                                      \
        G1  = g[tn * (long)BATCH + gf1];                                      \
    }                                                                         \
    BAR();                                                                    \
} while (0)

    for (int t = 0; t < T_STEPS; t += 2) {
        RSTEP(t,     z0A, a0A, g0A, z1A, a1A, g1A);
        RSTEP(t + 1, z0B, a0B, g0B, z1B, a1B, g1B);
    }
#undef RSTEP

    *(f4v*)&hfin[zf0] = hl0;
    *(f4v*)&hfin[zf1] = hl1;
}

extern "C" void kernel_launch(void* const* d_in, const int* in_sizes, int n_in,
                              void* d_out, int out_size, void* d_ws, size_t ws_size,
                              hipStream_t stream) {
    const float* x   = (const float*)d_in[0];
    const float* h0  = (const float*)d_in[1];
    const float* g   = (const float*)d_in[2];
    const float* a   = (const float*)d_in[3];
    const float* Wc1 = (const float*)d_in[4];
    const float* bc1 = (const float*)d_in[5];
    const float* Wc2 = (const float*)d_in[6];
    const float* bc2 = (const float*)d_in[7];
    const float* Wp1 = (const float*)d_in[8];
    const float* bp1 = (const float*)d_in[9];
    const float* Wp2 = (const float*)d_in[10];
    const float* bp2 = (const float*)d_in[11];

    float* outs = (float*)d_out;
    float* hfin = outs + (long)T_STEPS * BATCH * HDIM;
    float* capt = hfin + (long)BATCH * HDIM;

    capture_k<<<512, 256, 0, stream>>>(x, Wc1, bc1, Wc2, bc2, capt);
    recur_k<<<BATCH / 32, 256, 0, stream>>>(h0, g, a, Wp1, bp1, Wp2, bp2, capt, outs, hfin);
}

// Round 12
// 769.266 us; speedup vs baseline: 7.0610x; 1.5075x over previous
//
#include <hip/hip_runtime.h>
#include <hip/hip_bf16.h>

#define T_STEPS 512
#define BATCH   4096
#define ACT     16
#define HDIM    64

typedef short s8v __attribute__((ext_vector_type(8)));   // 8 bf16 MFMA A/B frag
typedef float f4v __attribute__((ext_vector_type(4)));   // MFMA C/D frag

#define MFMA16(A, B, C) __builtin_amdgcn_mfma_f32_16x16x32_bf16((A), (B), (C), 0, 0, 0)

__device__ __forceinline__ unsigned pkbf(float a, float b) {
    unsigned r;
    asm("v_cvt_pk_bf16_f32 %0, %1, %2" : "=v"(r) : "v"(a), "v"(b));
    return r;
}
__device__ __forceinline__ float hi16f(unsigned p) { return __builtin_bit_cast(float, p & 0xFFFF0000u); }
__device__ __forceinline__ unsigned short f2bf(float f) {
    unsigned u = __builtin_bit_cast(unsigned, f);
    u += 0x7FFFu + ((u >> 16) & 1u);
    return (unsigned short)(u >> 16);
}
__device__ __forceinline__ float bf2f(unsigned short b) {
    return __builtin_bit_cast(float, ((unsigned)b) << 16);
}
__device__ __forceinline__ float ftanh(float x) {
    float e = __expf(2.0f * x);
    return fmaf(-2.0f, __builtin_amdgcn_rcpf(e + 1.0f), 1.0f);
}
struct i4x { int a, b, c, d; };
// 4 f32 -> interleaved (hi,lo) bf16 pairs
__device__ __forceinline__ s8v pack4(f4v v) {
    unsigned p0 = pkbf(v[0], v[0]); float r0 = v[0] - hi16f(p0);
    unsigned p1 = pkbf(v[1], v[1]); float r1 = v[1] - hi16f(p1);
    unsigned p2 = pkbf(v[2], v[2]); float r2 = v[2] - hi16f(p2);
    unsigned p3 = pkbf(v[3], v[3]); float r3 = v[3] - hi16f(p3);
    i4x w{(int)pkbf(v[0], r0), (int)pkbf(v[1], r1), (int)pkbf(v[2], r2), (int)pkbf(v[3], r3)};
    return __builtin_bit_cast(s8v, w);
}
// raw barrier: drain LDS only; global loads/stores stay in flight
#define BAR() do { \
    asm volatile("s_waitcnt lgkmcnt(0)" ::: "memory"); \
    __builtin_amdgcn_s_barrier(); \
    asm volatile("" ::: "memory"); \
} while (0)

// ================= K1: capture (z1 for all T*B rows) — R8 proven config =================
__global__ __launch_bounds__(256, 1) void capture_k(
    const float* __restrict__ x,
    const float* __restrict__ Wc1, const float* __restrict__ bc1,
    const float* __restrict__ Wc2, const float* __restrict__ bc2,
    float* __restrict__ capt)
{
    const int tid = threadIdx.x;
    const int l   = tid & 63;
    const int m   = l & 15;
    const int q   = l >> 4;
    const int gw  = blockIdx.x * 4 + (tid >> 6);   // 0..1023
    const int NW  = 1024;
    const long NT = (long)T_STEPS * BATCH / 16;    // 131072 tiles

    s8v C1[4][4], C2h[4][4], C2l[4][4];
    f4v d1v[4], d2v[4];
    #pragma unroll
    for (int T = 0; T < 4; ++T) {
        #pragma unroll
        for (int f = 0; f < 4; ++f) {
            #pragma unroll
            for (int e = 0; e < 8; ++e) {
                const int j = f * 16 + q * 4 + (e >> 1);
                C1[T][f][e] = (short)f2bf(Wc1[j * 64 + 16 * T + m]);
                float v2 = Wc2[j * 64 + 16 * T + m];
                unsigned short h2 = f2bf(v2);
                C2h[T][f][e] = (short)h2;
                C2l[T][f][e] = (short)f2bf(v2 - bf2f(h2));
            }
        }
        d1v[T] = *(const f4v*)&bc1[16 * T + 4 * q];
        d2v[T] = *(const f4v*)&bc2[16 * T + 4 * q];
    }

    long tile = gw;
    if (tile >= NT) return;
    f4v XC[4];
    #pragma unroll
    for (int f = 0; f < 4; ++f)
        XC[f] = *(const f4v*)&x[(tile * 16 + m) * 64 + 16 * f + 4 * q];

    for (; tile < NT; tile += NW) {
        const long nxt = (tile + NW < NT) ? tile + NW : tile;
        f4v XN[4];
        #pragma unroll
        for (int f = 0; f < 4; ++f)
            XN[f] = *(const f4v*)&x[(nxt * 16 + m) * 64 + 16 * f + 4 * q];

        s8v xf[4];
        #pragma unroll
        for (int f = 0; f < 4; ++f) xf[f] = pack4(XC[f]);

        s8v tcf[4];
        #pragma unroll
        for (int T = 0; T < 4; ++T) {
            f4v u0 = d1v[T];
            f4v u1 = {0.f, 0.f, 0.f, 0.f};
            u0 = MFMA16(C1[T][0], xf[0], u0);
            u1 = MFMA16(C1[T][1], xf[1], u1);
            u0 = MFMA16(C1[T][2], xf[2], u0);
            u1 = MFMA16(C1[T][3], xf[3], u1);
            f4v tv;
            #pragma unroll
            for (int r = 0; r < 4; ++r) tv[r] = ftanh(u0[r] + u1[r]);
            tcf[T] = pack4(tv);
        }
        #pragma unroll
        for (int T = 0; T < 4; ++T) {
            f4v c0 = d2v[T];
            f4v c1 = {0.f, 0.f, 0.f, 0.f}, c2 = c1, c3 = c1;
            c0 = MFMA16(C2h[T][0], tcf[0], c0);
            c1 = MFMA16(C2h[T][1], tcf[1], c1);
            c2 = MFMA16(C2h[T][2], tcf[2], c2);
            c3 = MFMA16(C2h[T][3], tcf[3], c3);
            c0 = MFMA16(C2l[T][0], tcf[0], c0);
            c1 = MFMA16(C2l[T][1], tcf[1], c1);
            c2 = MFMA16(C2l[T][2], tcf[2], c2);
            c3 = MFMA16(C2l[T][3], tcf[3], c3);
            f4v zv;
            #pragma unroll
            for (int r = 0; r < 4; ++r) zv[r] = ftanh((c0[r] + c1[r]) + (c2[r] + c3[r]));
            *(f4v*)&capt[(tile * 16 + m) * 64 + 16 * T + 4 * q] = zv;
        }
        #pragma unroll
        for (int f = 0; f < 4; ++f) XC[f] = XN[f];
    }
}

// ================= K2: recurrence — redundant-L1, ONE barrier/step =================
// Wave T holds ALL W1 tiles and computes the full t1 in-register from the shared h
// frags; only the h exchange remains (4 ds_read + 1 ds_write + 1 barrier per step).
__global__ __launch_bounds__(256, 1) void recur_k(
    const float* __restrict__ h0, const float* __restrict__ g,
    const float* __restrict__ a,  const float* __restrict__ Wp1,
    const float* __restrict__ bp1, const float* __restrict__ Wp2,
    const float* __restrict__ bp2, const float* __restrict__ z1,
    float* __restrict__ outs, float* __restrict__ hfin)
{
    __shared__ s8v hx[2][4][64];   // double-buffered h frags (8 KB)

    const int tid = threadIdx.x;
    const int T   = tid >> 6;      // owned L2 tile
    const int l   = tid & 63;
    const int m   = l & 15;
    const int q   = l >> 4;
    const int b0  = blockIdx.x << 4;

    // ---- weights: W1 for ALL tiles (redundant-L1), W2 own tile hi/lo ----
    s8v W1a[4][5];
    f4v b1v[4];
    #pragma unroll
    for (int o = 0; o < 4; ++o) {
        #pragma unroll
        for (int f = 0; f < 4; ++f)
            #pragma unroll
            for (int e = 0; e < 8; ++e) {
                const int j = f * 16 + q * 4 + (e >> 1);
                W1a[o][f][e] = (short)f2bf(Wp1[j * 64 + 16 * o + m]);
            }
        #pragma unroll
        for (int e = 0; e < 8; ++e) {
            const int j = 64 + q * 4 + (e >> 1);
            W1a[o][4][e] = (short)f2bf(Wp1[j * 64 + 16 * o + m]);
        }
        b1v[o] = *(const f4v*)&bp1[16 * o + 4 * q];
    }
    s8v W2h[4], W2l[4];
    #pragma unroll
    for (int f = 0; f < 4; ++f)
        #pragma unroll
        for (int e = 0; e < 8; ++e) {
            const int j = f * 16 + q * 4 + (e >> 1);
            float v2 = Wp2[j * 64 + 16 * T + m];
            unsigned short h2 = f2bf(v2);
            W2h[f][e] = (short)h2;
            W2l[f][e] = (short)f2bf(v2 - bf2f(h2));
        }
    const f4v b2v = *(const f4v*)&bp2[16 * T + 4 * q];

    const long zoff = (long)(b0 + m) * 64 + 16 * T + 4 * q;
    const long aoff = (long)(b0 + m) * ACT + 4 * q;
    const long goff = (long)(b0 + m);

    hx[0][T][l] = pack4(*(const f4v*)&h0[zoff]);

    // depth-4 register prefetch rings
    f4v zP0 = *(const f4v*)&z1[0 * (long)BATCH * 64 + zoff];
    f4v zP1 = *(const f4v*)&z1[1 * (long)BATCH * 64 + zoff];
    f4v zP2 = *(const f4v*)&z1[2 * (long)BATCH * 64 + zoff];
    f4v zP3 = *(const f4v*)&z1[3 * (long)BATCH * 64 + zoff];
    f4v aP0 = *(const f4v*)&a[0 * (long)BATCH * ACT + aoff];
    f4v aP1 = *(const f4v*)&a[1 * (long)BATCH * ACT + aoff];
    f4v aP2 = *(const f4v*)&a[2 * (long)BATCH * ACT + aoff];
    f4v aP3 = *(const f4v*)&a[3 * (long)BATCH * ACT + aoff];
    float gP0 = g[0 * (long)BATCH + goff], gP1 = g[1 * (long)BATCH + goff];
    float gP2 = g[2 * (long)BATCH + goff], gP3 = g[3 * (long)BATCH + goff];

    float* outp = &outs[zoff];
    f4v hl = {0.f, 0.f, 0.f, 0.f};
    __syncthreads();

#define L1T(o, dst) {                                                         \
    f4v p0 = b1v[o];                                                          \
    f4v p1 = {0.f, 0.f, 0.f, 0.f}, p2 = p1;                                   \
    p0 = MFMA16(W1a[o][0], hf0, p0);                                          \
    p1 = MFMA16(W1a[o][1], hf1, p1);                                          \
    p2 = MFMA16(W1a[o][2], hf2, p2);                                          \
    p0 = MFMA16(W1a[o][3], hf3, p0);                                          \
    p1 = MFMA16(W1a[o][4], afr, p1);                                          \
    f4v tv_;                                                                  \
    _Pragma("unroll")                                                         \
    for (int r = 0; r < 4; ++r) tv_[r] = ftanh((p0[r] + p1[r]) + p2[r]);      \
    dst = pack4(tv_);                                                         \
}

#define RSTEP(tt, PAR, ZP, AP, GP) do {                                       \
    const s8v hf0 = hx[PAR][0][l];                                            \
    const s8v hf1 = hx[PAR][1][l];                                            \
    const s8v hf2 = hx[PAR][2][l];                                            \
    const s8v hf3 = hx[PAR][3][l];                                            \
    const s8v afr = pack4(AP);                                                \
    s8v t1f0, t1f1, t1f2, t1f3;                                               \
    L1T(0, t1f0) L1T(1, t1f1) L1T(2, t1f2) L1T(3, t1f3)                       \
    f4v c0 = b2v;                                                             \
    f4v c1 = {0.f, 0.f, 0.f, 0.f}, c2 = c1, c3 = c1;                          \
    c0 = MFMA16(W2h[0], t1f0, c0); c1 = MFMA16(W2h[1], t1f1, c1);             \
    c2 = MFMA16(W2h[2], t1f2, c2); c3 = MFMA16(W2h[3], t1f3, c3);             \
    c0 = MFMA16(W2l[0], t1f0, c0); c1 = MFMA16(W2l[1], t1f1, c1);             \
    c2 = MFMA16(W2l[2], t1f2, c2); c3 = MFMA16(W2l[3], t1f3, c3);             \
    f4v hv;                                                                   \
    _Pragma("unroll")                                                         \
    for (int r = 0; r < 4; ++r) {                                             \
        float z2 = ftanh((c0[r] + c1[r]) + (c2[r] + c3[r]));                  \
        hv[r] = fmaf(GP, z2 - ZP[r], ZP[r]);                                  \
    }                                                                         \
    *(f4v*)outp = hv;                                                         \
    outp += (long)BATCH * HDIM;                                               \
    hl = hv;                                                                  \
    hx[PAR ^ 1][T][l] = pack4(hv);                                            \
    {                                                                         \
        const long tn = ((tt) + 4 < T_STEPS) ? (tt) + 4 : T_STEPS - 1;        \
        ZP = *(const f4v*)&z1[tn * (long)BATCH * 64 + zoff];                  \
        AP = *(const f4v*)&a[tn * (long)BATCH * ACT + aoff];                  \
        GP = g[tn * (long)BATCH + goff];                                      \
    }                                                                         \
    BAR();                                                                    \
} while (0)

    for (int t = 0; t < T_STEPS; t += 4) {
        RSTEP(t + 0, 0, zP0, aP0, gP0);
        RSTEP(t + 1, 1, zP1, aP1, gP1);
        RSTEP(t + 2, 0, zP2, aP2, gP2);
        RSTEP(t + 3, 1, zP3, aP3, gP3);
    }
#undef RSTEP
#undef L1T

    *(f4v*)&hfin[zoff] = hl;
}

extern "C" void kernel_launch(void* const* d_in, const int* in_sizes, int n_in,
                              void* d_out, int out_size, void* d_ws, size_t ws_size,
                              hipStream_t stream) {
    const float* x   = (const float*)d_in[0];
    const float* h0  = (const float*)d_in[1];
    const float* g   = (const float*)d_in[2];
    const float* a   = (const float*)d_in[3];
    const float* Wc1 = (const float*)d_in[4];
    const float* bc1 = (const float*)d_in[5];
    const float* Wc2 = (const float*)d_in[6];
    const float* bc2 = (const float*)d_in[7];
    const float* Wp1 = (const float*)d_in[8];
    const float* bp1 = (const float*)d_in[9];
    const float* Wp2 = (const float*)d_in[10];
    const float* bp2 = (const float*)d_in[11];

    float* outs = (float*)d_out;
    float* hfin = outs + (long)T_STEPS * BATCH * HDIM;
    float* capt = hfin + (long)BATCH * HDIM;

    capture_k<<<256, 256, 0, stream>>>(x, Wc1, bc1, Wc2, bc2, capt);
    recur_k<<<BATCH / 16, 256, 0, stream>>>(h0, g, a, Wp1, bp1, Wp2, bp2, capt, outs, hfin);
}